// Round 8
// baseline (135.525 us; speedup 1.0000x reference)
//
#include <hip/hip_runtime.h>
#include <math.h>

// SSIM loss, fp32 in, B=16 C=3 H=W=512, 11x11 Gaussian (sigma=1.5), zero pad.
// R17: zero-LDS pipeline — bpermute in-register transpose + carry-acc vconv.
//   R16 post-mortem: guaranteed 12-deep asm load ring changed NOTHING vs
//   compiler-scheduled (42.3 vs 42.5 us) -> wave-side load scheduling is not
//   the limiter. Remaining per-wave serial segment: the Ht LDS round-trip
//   (ds_write -> lgkm -> ds_read each chunk) + occupancy pinned ~10-12
//   waves/CU for 6 rounds. Fix both:
//   - vconv B-frag built by 4x ds_bpermute_b32 per plane from the packed
//     hconv D output (lane (q',fc) pulls dwords from lanes 32*(q'&1)+fc and
//     +16) -> NO Ht storage, no write->read ordering, all 16 bpermutes
//     independent.
//   - vconv = R14's VERIFIED carry-accumulate: out chunk m accumulates
//     MFMA(wvA1,B(m)) at c=m and MFMA(wvA2,B(m+1)) at c=m+1; single acc set
//     (finish-then-start reuses B and acc registers).
//   - tile kernel uses ZERO LDS (per-wave partials, no barriers) -> no LDS
//     occupancy bound; launch_bounds(256,4).
// Math identical to R10-R16 (S=x+y, D=x-y planes, f16 pipeline, cv fixup).
// gfx950 v_mfma_f32_16x16x32_f16 layouts (verified R10-R16 pass):
//   A[i][k]: lane = i + 16*(k/8), elem = k%8
//   B[k][j]: lane = j + 16*(k/8), elem = k%8
//   D[r][c]: lane = c + 16*(r/4), reg  = r%4

#define IMG_W 512
#define IMG_H 512
#define PLANES 48
#define TX 64
#define TYS 128
#define RAD 5
#define NT 256
#define GDX (IMG_W / TX)            // 8
#define GDY (IMG_H / TYS)           // 4
#define NBLK (GDX * GDY * PLANES)   // 1536
#define NWAVES (NBLK * 4)           // 6144
#define NCH 9                       // hconv 16-row chunks (144 H rows)
#define NUMREC (IMG_W * IMG_H * 4)  // SRD num_records (bytes)
#define CHSTEP (16 * IMG_W * 4)     // voffset step per 16-row chunk (32768)
#define INVW  0.26601181f           // 1 / sum(exp(-(k-5)^2/4.5))
#define GC2   0.32059890f           // (1/4.5) * log2(e)

typedef _Float16 h2 __attribute__((ext_vector_type(2)));
typedef _Float16 h8 __attribute__((ext_vector_type(8)));
typedef float f32x4 __attribute__((ext_vector_type(4)));
typedef int i32x4 __attribute__((ext_vector_type(4)));

// CK-style direct binding to the raw buffer-load intrinsic: hardware
// bounds-check vs num_records; OOB lanes read 0 (zero-pad for free).
__device__ f32x4 buf_ld_x4(i32x4 srsrc, int voffset, int soffset, int aux)
    __asm("llvm.amdgcn.raw.buffer.load.v4f32");

__device__ __forceinline__ i32x4 make_srd(const float* p) {
    union { i32x4 v; struct { const float* p; unsigned rng; unsigned cfg; } s; } u;
    u.s.p = p; u.s.rng = NUMREC; u.s.cfg = 0x00020000u;
    return u.v;
}

__device__ __forceinline__ float exp2_fast(float a) {
#if __has_builtin(__builtin_amdgcn_exp2f)
    return __builtin_amdgcn_exp2f(a);
#else
    return exp2f(a);
#endif
}

// Normalized f32 Gaussian weight w[idx], idx in [0,10], else 0.
__device__ __forceinline__ float wbandf(int idx) {
    const float fd = (float)(idx - 5);
    const float g = exp2_fast(-(fd * fd) * GC2) * INVW;
    return ((unsigned)idx <= 10u) ? g : 0.f;
}

__device__ __forceinline__ h2 pkrtz(float a, float b) {
    auto t = __builtin_amdgcn_cvt_pkrtz(a, b);
    h2 r;
    __builtin_memcpy(&r, &t, sizeof(r));
    return r;
}

// Pack f32x4 (4 D rows) to two dwords of f16 pairs.
__device__ __forceinline__ void packdw(f32x4 a, int& d0, int& d1) {
    const h2 lo = pkrtz(a[0], a[1]), hi = pkrtz(a[2], a[3]);
    __builtin_memcpy(&d0, &lo, 4);
    __builtin_memcpy(&d1, &hi, 4);
}

// Build vconv B-frag from packed hconv dwords via 4 bpermutes.
// Lane (q',fc): k rows 8q'..+3 from src lane 32*(q'&1)+fc (idxA), rows
// +4..+7 from src lane +16 (idxB). k>=16 lanes (q'>=2) are don't-care
// (their vconv band weights are 0).
__device__ __forceinline__ h8 bperm_frag(int idxA, int idxB, int pd0, int pd1) {
    const int b0 = __builtin_amdgcn_ds_bpermute(idxA, pd0);
    const int b1 = __builtin_amdgcn_ds_bpermute(idxA, pd1);
    const int b2 = __builtin_amdgcn_ds_bpermute(idxB, pd0);
    const int b3 = __builtin_amdgcn_ds_bpermute(idxB, pd1);
    union { i32x4 i; h8 h; } u;
    u.i = i32x4{b0, b1, b2, b3};
    return u.h;
}

// SSIM map for one completed out-chunk (4 rows of one col per lane).
__device__ __forceinline__ float mapsum(f32x4 aS, f32x4 aD, f32x4 aS2, f32x4 aD2,
                                        float cv)
{
    float local = 0.f;
    #pragma unroll
    for (int r = 0; r < 4; ++r) {
        const float mS = aS[r]  * cv, mD = aD[r]  * cv;
        const float eS = aS2[r] * cv, eD = aD2[r] * cv;
        const float ms2 = mS * mS, md2 = mD * mD;
        const float Pm = 0.5f * (ms2 - md2);   // = 2*mu_x*mu_y
        const float Qm = 0.5f * (ms2 + md2);   // = mu_x^2 + mu_y^2
        const float Pe = 0.5f * (eS - eD);     // = 2*E[xy]
        const float Qe = 0.5f * (eS + eD);     // = E[x^2 + y^2]
        const float c1 = 1e-4f, c2 = 9e-4f;
        const float num = (Pm + c1) * (Pe - Pm + c2);
        const float den = (Qm + c1) * (Qe - Qm + c2) + 1e-8f;
        local += num * __builtin_amdgcn_rcpf(den);
    }
    return local;
}

#define MFMA16(A, B, C) __builtin_amdgcn_mfma_f32_16x16x32_f16((A), (B), (C), 0, 0, 0)

__global__ __launch_bounds__(NT, 4) void ssim_tile_kernel(
    const float* __restrict__ x, const float* __restrict__ y,
    float* __restrict__ partials)
{
    const int tid = threadIdx.x;
    const int l = tid & 63, wid = tid >> 6;
    const int q = l >> 4, fc = l & 15;

    const int plane = blockIdx.z;
    const i32x4 srdx = make_srd(x + (size_t)plane * IMG_H * IMG_W);
    const i32x4 srdy = make_srd(y + (size_t)plane * IMG_H * IMG_W);
    const int C0 = blockIdx.x * TX;
    const int R0 = blockIdx.y * TYS;
    const int c0 = 16 * wid;                    // this wave's out-col base
    const int gcol = C0 + c0 - 8 + 8 * q;       // A-frag global col start
    // Row OOB -> voffset outside [0,NUMREC) -> HW returns 0 (zero-pad).
    // Col OOB lanes (gcol=-8 or 512): permanently-OOB voffset.
    int voff = ((unsigned)gcol < (unsigned)IMG_W)
             ? (((R0 - RAD + fc) << 11) + (gcol << 2)) : 0x60000000;

    // bpermute indices (bytes): src lanes 32*(q'&1)+fc and +16.
    const int idxA = ((l & 16) << 3) | ((l & 15) << 2);
    const int idxB = idxA + 64;

    // ---- Prologue: issue chunks 0,1 into reg ring slots 0,1 ----
    f32x4 LXA[2], LXB[2], LYA[2], LYB[2];
    #pragma unroll
    for (int cpl = 0; cpl < 2; ++cpl) {
        LXA[cpl] = buf_ld_x4(srdx, voff, 0, 0);
        LXB[cpl] = buf_ld_x4(srdx, voff, 16, 0);
        LYA[cpl] = buf_ld_x4(srdy, voff, 0, 0);
        LYB[cpl] = buf_ld_x4(srdy, voff, 16, 0);
        voff += CHSTEP;
    }

    // ---- Weight setup (executes under the in-flight loads) ----
    float s2w = 0.f;
    #pragma unroll
    for (int k = 0; k <= 10; ++k) s2w += (float)(_Float16)wbandf(k);
    const float cv = 1.f / (s2w * s2w);

    h8 whB, wvA1, wvA2;
    #pragma unroll
    for (int e = 0; e < 8; ++e) {
        const int k = 8 * q + e;
        whB[e]  = (_Float16)wbandf(k - fc - 3);                     // hconv band
        wvA1[e] = (_Float16)((k < 16) ? wbandf(k - fc)      : 0.f); // vconv lo
        wvA2[e] = (_Float16)((k < 16) ? wbandf(k + 16 - fc) : 0.f); // vconv hi
    }

    const f32x4 zz = {0.f, 0.f, 0.f, 0.f};
    f32x4 acc[4];                    // single acc set (finish before start)
    float local = 0.f;

    // ---- Main loop over hconv chunks c = 0..8 (fully unrolled) ----
    // Out chunk m: VSTART at c=m (wvA1 x B(m)), VFINISH at c=m+1 (wvA2 x
    // B(m+1)).  B(c) built from chunk c's packed hconv output via bpermute.
    #pragma unroll
    for (int c = 0; c < NCH; ++c) {
        // hconv chunk c from ring slot
        const f32x4 xa = LXA[c & 1], xb = LXB[c & 1];
        const f32x4 ya = LYA[c & 1], yb = LYB[c & 1];
        if (c + 2 < NCH) {                       // refill ring with chunk c+2
            LXA[c & 1] = buf_ld_x4(srdx, voff, 0, 0);
            LXB[c & 1] = buf_ld_x4(srdx, voff, 16, 0);
            LYA[c & 1] = buf_ld_x4(srdy, voff, 0, 0);
            LYB[c & 1] = buf_ld_x4(srdy, voff, 16, 0);
            voff += CHSTEP;
        }
        const h2 xh0 = pkrtz(xa[0], xa[1]), xh1 = pkrtz(xa[2], xa[3]);
        const h2 xh2 = pkrtz(xb[0], xb[1]), xh3 = pkrtz(xb[2], xb[3]);
        const h2 yh0 = pkrtz(ya[0], ya[1]), yh1 = pkrtz(ya[2], ya[3]);
        const h2 yh2 = pkrtz(yb[0], yb[1]), yh3 = pkrtz(yb[2], yb[3]);
        const h2 s0 = xh0 + yh0, s1 = xh1 + yh1, s2 = xh2 + yh2, s3 = xh3 + yh3;
        const h2 d0 = xh0 - yh0, d1 = xh1 - yh1, d2 = xh2 - yh2, d3 = xh3 - yh3;
        h8 sA, dA;
        sA[0] = s0.x; sA[1] = s0.y; sA[2] = s1.x; sA[3] = s1.y;
        sA[4] = s2.x; sA[5] = s2.y; sA[6] = s3.x; sA[7] = s3.y;
        dA[0] = d0.x; dA[1] = d0.y; dA[2] = d1.x; dA[3] = d1.y;
        dA[4] = d2.x; dA[5] = d2.y; dA[6] = d3.x; dA[7] = d3.y;
        const h8 s2A = sA * sA;                  // v_pk_mul_f16
        const h8 d2A = dA * dA;
        const f32x4 hS  = MFMA16(sA,  whB, zz);
        const f32x4 hD  = MFMA16(dA,  whB, zz);
        const f32x4 hS2 = MFMA16(s2A, whB, zz);
        const f32x4 hD2 = MFMA16(d2A, whB, zz);

        // pack D (4 rows f32 -> 2 dwords f16) and transpose via bpermute
        int pd0, pd1;
        h8 B[4];
        packdw(hS,  pd0, pd1); B[0] = bperm_frag(idxA, idxB, pd0, pd1);
        packdw(hD,  pd0, pd1); B[1] = bperm_frag(idxA, idxB, pd0, pd1);
        packdw(hS2, pd0, pd1); B[2] = bperm_frag(idxA, idxB, pd0, pd1);
        packdw(hD2, pd0, pd1); B[3] = bperm_frag(idxA, idxB, pd0, pd1);

        // vconv: finish out-chunk c-1, then start out-chunk c (reuses acc)
        if (c >= 1) {
            const f32x4 fS  = MFMA16(wvA2, B[0], acc[0]);
            const f32x4 fD  = MFMA16(wvA2, B[1], acc[1]);
            const f32x4 fS2 = MFMA16(wvA2, B[2], acc[2]);
            const f32x4 fD2 = MFMA16(wvA2, B[3], acc[3]);
            local += mapsum(fS, fD, fS2, fD2, cv);
        }
        if (c < NCH - 1) {
            acc[0] = MFMA16(wvA1, B[0], zz);
            acc[1] = MFMA16(wvA1, B[1], zz);
            acc[2] = MFMA16(wvA1, B[2], zz);
            acc[3] = MFMA16(wvA1, B[3], zz);
        }
    }

    // ---- Wave reduction -> one partial per wave (no barrier, no LDS) ----
    #pragma unroll
    for (int off = 32; off > 0; off >>= 1)
        local += __shfl_down(local, off, 64);
    const int gid = (blockIdx.x + GDX * (blockIdx.y + GDY * blockIdx.z)) * 4 + wid;
    if (l == 0) partials[gid] = local;
}

__global__ __launch_bounds__(256) void ssim_finalize_kernel(
    const float* __restrict__ partials, float* __restrict__ out)
{
    const int tid = threadIdx.x;
    double s = 0.0;
    #pragma unroll 4
    for (int i = tid; i < NWAVES; i += 256) s += (double)partials[i];
    #pragma unroll
    for (int off = 32; off > 0; off >>= 1)
        s += __shfl_down(s, off, 64);
    __shared__ double ws_[256 / 64];
    const int lane = tid & 63, wv = tid >> 6;
    if (lane == 0) ws_[wv] = s;
    __syncthreads();
    if (tid == 0) {
        const double t = ws_[0] + ws_[1] + ws_[2] + ws_[3];
        const double n = (double)PLANES * IMG_H * IMG_W;
        out[0] = (float)(1.0 - t / n);
    }
}

extern "C" void kernel_launch(void* const* d_in, const int* in_sizes, int n_in,
                              void* d_out, int out_size, void* d_ws, size_t ws_size,
                              hipStream_t stream)
{
    const float* x = (const float*)d_in[0];
    const float* y = (const float*)d_in[1];
    float* out = (float*)d_out;
    float* partials = (float*)d_ws;   // NWAVES floats, fully overwritten each call

    dim3 grid(GDX, GDY, PLANES);
    ssim_tile_kernel<<<grid, NT, 0, stream>>>(x, y, partials);
    ssim_finalize_kernel<<<1, 256, 0, stream>>>(partials, out);
}